// Round 1
// baseline (515.208 us; speedup 1.0000x reference)
//
#include <hip/hip_runtime.h>

// Multi-scale morphological closing with parabolic structuring elements.
// Reference: 4 scales, SE half-widths w_k = {4,8,16,32}, weights (1/(4*t_k))*x^2,
// t_k = 4^k. closing_k = erode_v(erode_h(dilate_v(dilate_h(x)))) per scale.
// Padding ±10000 never wins the max/min (data bounded ~±6, tap j=w has weight 0),
// so out-of-range taps are simply skipped — bit-exact vs the padded reference.

#define HH 256
#define WW 256
#define BC 32            // B*C = 4*8
#define NS 4             // n_scales
#define HW (HH * WW)

// IS_MAX: dilation (v - wt, max) vs erosion (v + wt, min)
// HORIZ:  window along W vs along H
template <bool IS_MAX, bool HORIZ>
__global__ void pool_kernel(const float* __restrict__ in, float* __restrict__ out,
                            const float* __restrict__ cptr,
                            int wk, float inv4t,
                            long in_zs, long out_zs)
{
    const int x = threadIdx.x;   // 0..255 : W
    const int h = blockIdx.x;    // 0..255 : H
    const int z = blockIdx.y;    // 0..31  : B*C image index

    const float cw = cptr[0] * inv4t;   // c / (4*t_k)
    const int n = 2 * wk + 1;

    const float* img = in + (long)z * in_zs;
    float acc = IS_MAX ? -1e30f : 1e30f;

    if (HORIZ) {
        const float* row = img + h * WW;
        const int jlo = max(0, wk - x);
        const int jhi = min(n, WW + wk - x);
        for (int j = jlo; j < jhi; ++j) {
            const float d = (float)(j - wk);
            const float v = row[x + j - wk];
            const float wt = cw * d * d;
            acc = IS_MAX ? fmaxf(acc, v - wt) : fminf(acc, v + wt);
        }
    } else {
        const int jlo = max(0, wk - h);
        const int jhi = min(n, HH + wk - h);
        for (int j = jlo; j < jhi; ++j) {
            const float d = (float)(j - wk);
            const float v = img[(h + j - wk) * WW + x];
            const float wt = cw * d * d;
            acc = IS_MAX ? fmaxf(acc, v - wt) : fminf(acc, v + wt);
        }
    }

    out[(long)z * out_zs + h * WW + x] = acc;
}

extern "C" void kernel_launch(void* const* d_in, const int* in_sizes, int n_in,
                              void* d_out, int out_size, void* d_ws, size_t ws_size,
                              hipStream_t stream)
{
    const float* x   = (const float*)d_in[0];   // [4,8,256,256] fp32
    const float* c   = (const float*)d_in[1];   // scalar se_coef
    float* out = (float*)d_out;                 // [4,8,4,256,256] fp32
    float* tmp = (float*)d_ws;                  // needs 8 MB (BC*H*W fp32)

    static const int   wks[NS]   = {4, 8, 16, 32};
    static const float inv4t[NS] = {0.25f, 0.0625f, 1.0f / 64.0f, 1.0f / 256.0f};

    dim3 grid(HH, BC);
    dim3 block(WW);

    for (int k = 0; k < NS; ++k) {
        float* outk = out + (long)k * HW;   // scale-k slice; z-stride NS*HW

        // dilate_h : input -> ws
        pool_kernel<true, true><<<grid, block, 0, stream>>>(
            x, tmp, c, wks[k], inv4t[k], (long)HW, (long)HW);
        // dilate_v : ws -> out slice k
        pool_kernel<true, false><<<grid, block, 0, stream>>>(
            tmp, outk, c, wks[k], inv4t[k], (long)HW, (long)NS * HW);
        // erode_h : out slice k -> ws
        pool_kernel<false, true><<<grid, block, 0, stream>>>(
            outk, tmp, c, wks[k], inv4t[k], (long)NS * HW, (long)HW);
        // erode_v : ws -> out slice k (final)
        pool_kernel<false, false><<<grid, block, 0, stream>>>(
            tmp, outk, c, wks[k], inv4t[k], (long)HW, (long)NS * HW);
    }
}

// Round 2
// 358.382 us; speedup vs baseline: 1.4376x; 1.4376x over previous
//
#include <hip/hip_runtime.h>

// Multi-scale parabolic morphological closing, register-blocked.
// closing_k = erode_v(erode_h(dilate_v(dilate_h(x)))), w_k = {4,8,16,32},
// weight_k(d) = c * d^2 * (4/W^2)  (power-of-two scaling -> bit-exact vs ref).
// Pad value +-1e30 never wins max/min vs real data -> identical to ref's +-10000 pad.

#define HH 256
#define WW 256
#define BC 32            // B*C
#define NS 4
#define HW (HH * WW)
#define LDS_STRIDE 324   // floats per LDS row (2*32+256+4; mod 32 == 4 breaks r-conflicts)
#define LDS_BYTES (8 * LDS_STRIDE * 4)

// ---------------- H pass: thread owns 8 consecutive outputs in a row ----------------
template <int W, bool IS_MAX>
__device__ __forceinline__ void hpass_impl(const float* __restrict__ in,
                                           float* __restrict__ out,
                                           float cw, float* lbuf)
{
    const int tid = threadIdx.x;
    const int r = tid >> 5;      // 0..7  row within block
    const int t = tid & 31;      // 0..31 column group (outputs 8t..8t+7)
    const int rg = blockIdx.y;   // 0..31 row group
    const int row = rg * 8 + r;
    const float PAD = IS_MAX ? -1e30f : 1e30f;

    // stage padded row into LDS (coalesced float4 loads)
    const float* rowp = in + (long)row * WW;
    float4 v0 = *(const float4*)(rowp + 4 * t);
    float4 v1 = *(const float4*)(rowp + 128 + 4 * t);
    float* lr = lbuf + r * LDS_STRIDE;
    *(float4*)(lr + W + 4 * t) = v0;
    *(float4*)(lr + W + 128 + 4 * t) = v1;
    if (t < W) { lr[t] = PAD; lr[W + 256 + t] = PAD; }
    __syncthreads();

    float wts[W + 1];
#pragma unroll
    for (int a = 0; a <= W; ++a) wts[a] = cw * (float)(a * a);

    float acc[8];
#pragma unroll
    for (int pp = 0; pp < 8; ++pp) acc[pp] = PAD;

    const float* lw = lr + 8 * t;   // jj=0 <-> global col 8t-W
#pragma unroll
    for (int u = 0; u < W + 4; ++u) {
        float2 v = *(const float2*)(lw + 2 * u);
#pragma unroll
        for (int pp = 0; pp < 8; ++pp) {
            const int d1 = 2 * u - W - pp;
            const int d2 = d1 + 1;
            const bool ok1 = (d1 >= -W) && (d1 <= W);
            const bool ok2 = (d2 >= -W) && (d2 <= W);
            const int a1 = d1 < 0 ? -d1 : d1;
            const int a2 = d2 < 0 ? -d2 : d2;
            if (ok1 && ok2) {
                float c1 = IS_MAX ? v.x - wts[a1] : v.x + wts[a1];
                float c2 = IS_MAX ? v.y - wts[a2] : v.y + wts[a2];
                acc[pp] = IS_MAX ? fmaxf(acc[pp], fmaxf(c1, c2))
                                 : fminf(acc[pp], fminf(c1, c2));
            } else if (ok1) {
                float c1 = IS_MAX ? v.x - wts[a1] : v.x + wts[a1];
                acc[pp] = IS_MAX ? fmaxf(acc[pp], c1) : fminf(acc[pp], c1);
            } else if (ok2) {
                float c2 = IS_MAX ? v.y - wts[a2] : v.y + wts[a2];
                acc[pp] = IS_MAX ? fmaxf(acc[pp], c2) : fminf(acc[pp], c2);
            }
        }
    }
    float* op = out + (long)row * WW + 8 * t;
    *(float4*)(op)     = make_float4(acc[0], acc[1], acc[2], acc[3]);
    *(float4*)(op + 4) = make_float4(acc[4], acc[5], acc[6], acc[7]);
}

// ---------------- V pass: thread owns 16 consecutive output rows in a column ----------------
template <int W, bool IS_MAX>
__device__ __forceinline__ void vpass_impl(const float* __restrict__ in,
                                           float* __restrict__ out,
                                           float cw)
{
    const int x = threadIdx.x;       // 0..255 column
    const int h0 = blockIdx.y * 16;  // 16 output rows per block
    const float PAD = IS_MAX ? -1e30f : 1e30f;

    float wts[W + 1];
#pragma unroll
    for (int a = 0; a <= W; ++a) wts[a] = cw * (float)(a * a);

    float acc[16];
#pragma unroll
    for (int pp = 0; pp < 16; ++pp) acc[pp] = PAD;

#pragma unroll
    for (int u = 0; u < W + 8; ++u) {
        const int h1 = h0 - W + 2 * u;
        const int h2 = h1 + 1;
        float v1, v2;
        if (h1 >= 0 && h1 < HH) v1 = in[(long)h1 * WW + x]; else v1 = PAD;  // uniform branch
        if (h2 >= 0 && h2 < HH) v2 = in[(long)h2 * WW + x]; else v2 = PAD;
#pragma unroll
        for (int pp = 0; pp < 16; ++pp) {
            const int d1 = 2 * u - W - pp;
            const int d2 = d1 + 1;
            const bool ok1 = (d1 >= -W) && (d1 <= W);
            const bool ok2 = (d2 >= -W) && (d2 <= W);
            const int a1 = d1 < 0 ? -d1 : d1;
            const int a2 = d2 < 0 ? -d2 : d2;
            if (ok1 && ok2) {
                float c1 = IS_MAX ? v1 - wts[a1] : v1 + wts[a1];
                float c2 = IS_MAX ? v2 - wts[a2] : v2 + wts[a2];
                acc[pp] = IS_MAX ? fmaxf(acc[pp], fmaxf(c1, c2))
                                 : fminf(acc[pp], fminf(c1, c2));
            } else if (ok1) {
                float c1 = IS_MAX ? v1 - wts[a1] : v1 + wts[a1];
                acc[pp] = IS_MAX ? fmaxf(acc[pp], c1) : fminf(acc[pp], c1);
            } else if (ok2) {
                float c2 = IS_MAX ? v2 - wts[a2] : v2 + wts[a2];
                acc[pp] = IS_MAX ? fmaxf(acc[pp], c2) : fminf(acc[pp], c2);
            }
        }
    }
#pragma unroll
    for (int pp = 0; pp < 16; ++pp) out[(long)(h0 + pp) * WW + x] = acc[pp];
}

// ---------------- global kernels: blockIdx.x = image z (XCD affinity), blockIdx.z = scale ----
template <bool IS_MAX>
__global__ __launch_bounds__(256) void hpass_all(const float* __restrict__ in,
                                                 float* __restrict__ out,
                                                 const float* __restrict__ cptr,
                                                 long in_ks, long in_zs,
                                                 long out_ks, long out_zs, int kbase)
{
    extern __shared__ float lbuf[];
    const int k = kbase + blockIdx.z;
    const int z = blockIdx.x;
    const float c = cptr[0];
    const float* ip = in + (long)blockIdx.z * in_ks + (long)z * in_zs;
    float* op = out + (long)blockIdx.z * out_ks + (long)z * out_zs;
    switch (k) {
        case 0: hpass_impl<4,  IS_MAX>(ip, op, c * (4.0f / (4 * 4)),   lbuf); break;
        case 1: hpass_impl<8,  IS_MAX>(ip, op, c * (4.0f / (8 * 8)),   lbuf); break;
        case 2: hpass_impl<16, IS_MAX>(ip, op, c * (4.0f / (16 * 16)), lbuf); break;
        case 3: hpass_impl<32, IS_MAX>(ip, op, c * (4.0f / (32 * 32)), lbuf); break;
    }
}

template <bool IS_MAX>
__global__ __launch_bounds__(256) void vpass_all(const float* __restrict__ in,
                                                 float* __restrict__ out,
                                                 const float* __restrict__ cptr,
                                                 long in_ks, long in_zs,
                                                 long out_ks, long out_zs, int kbase)
{
    const int k = kbase + blockIdx.z;
    const int z = blockIdx.x;
    const float c = cptr[0];
    const float* ip = in + (long)blockIdx.z * in_ks + (long)z * in_zs;
    float* op = out + (long)blockIdx.z * out_ks + (long)z * out_zs;
    switch (k) {
        case 0: vpass_impl<4,  IS_MAX>(ip, op, c * (4.0f / (4 * 4)));   break;
        case 1: vpass_impl<8,  IS_MAX>(ip, op, c * (4.0f / (8 * 8)));   break;
        case 2: vpass_impl<16, IS_MAX>(ip, op, c * (4.0f / (16 * 16))); break;
        case 3: vpass_impl<32, IS_MAX>(ip, op, c * (4.0f / (32 * 32))); break;
    }
}

extern "C" void kernel_launch(void* const* d_in, const int* in_sizes, int n_in,
                              void* d_out, int out_size, void* d_ws, size_t ws_size,
                              hipStream_t stream)
{
    const float* x = (const float*)d_in[0];   // [4,8,256,256] fp32
    const float* c = (const float*)d_in[1];   // scalar se_coef
    float* out = (float*)d_out;               // [4,8,4,256,256] fp32
    float* ws  = (float*)d_ws;

    const long SLICE = (long)BC * HW;         // floats per full-image slice

    if (ws_size >= (size_t)NS * SLICE * sizeof(float)) {
        // merged path: 4 launches, ws holds 4 slices
        dim3 hg(BC, 32, NS), vg(BC, 16, NS), blk(256);
        hpass_all<true ><<<hg, blk, LDS_BYTES, stream>>>(x,   ws,  c, 0,     HW,      SLICE, HW,      0);
        vpass_all<true ><<<vg, blk, 0,         stream>>>(ws,  out, c, SLICE, HW,      HW,    NS * HW, 0);
        hpass_all<false><<<hg, blk, LDS_BYTES, stream>>>(out, ws,  c, HW,    NS * HW, SLICE, HW,      0);
        vpass_all<false><<<vg, blk, 0,         stream>>>(ws,  out, c, SLICE, HW,      HW,    NS * HW, 0);
    } else {
        // fallback: 16 launches, single-slice ws ping-pong
        dim3 hg(BC, 32, 1), vg(BC, 16, 1), blk(256);
        for (int k = 0; k < NS; ++k) {
            float* outk = out + (long)k * HW;
            hpass_all<true ><<<hg, blk, LDS_BYTES, stream>>>(x,    ws,   c, 0, HW,      0, HW,      k);
            vpass_all<true ><<<vg, blk, 0,         stream>>>(ws,   outk, c, 0, HW,      0, NS * HW, k);
            hpass_all<false><<<hg, blk, LDS_BYTES, stream>>>(outk, ws,   c, 0, NS * HW, 0, HW,      k);
            vpass_all<false><<<vg, blk, 0,         stream>>>(ws,   outk, c, 0, HW,      0, NS * HW, k);
        }
    }
}

// Round 3
// 175.199 us; speedup vs baseline: 2.9407x; 2.0456x over previous
//
#include <hip/hip_runtime.h>

// Multi-scale parabolic morphological closing.
// closing_k = erode_v(erode_h(dilate_v(dilate_h(x)))), W_k = {4,8,16,32},
// weight(d) = c * (4/W^2) * d^2  (4/W^2 is a power of two -> cw*K exact for c=0.5,
// fmaf == ref's mul+sub bit-exactly). Out-of-range taps replaced by +-1e30 pad,
// which never wins vs ref's +-10000-weighted pad candidates (verified absmax 0).
//
// R3: no weight arrays (all K are compile-time literals), branchless clamped
// batched loads, 16 lean dispatches (no switch -> full unroll succeeds),
// launch_bounds(256,4). Root cause of R2's 138us vpass: failed unroll ->
// dynamic wts[] index -> scratch spill (VGPR=44, WRITE +16MB).

#define HH 256
#define WW 256
#define BC 32
#define NS 4
#define HW (HH * WW)

// ---------------- H pass: block = 8 rows; thread owns 8 consecutive cols ----------------
template <int W, bool IS_MAX>
__global__ __launch_bounds__(256, 4) void hpass_k(const float* __restrict__ in,
                                                  float* __restrict__ out,
                                                  const float* __restrict__ cptr,
                                                  long in_zs, long out_zs)
{
    __shared__ float lbuf[8 * 324];
    const int tid = threadIdx.x;
    const int r = tid >> 5;      // row within block
    const int t = tid & 31;      // column group
    const int z = blockIdx.x;    // image (z%8 -> fixed XCD: L2 locality)
    const int row = blockIdx.y * 8 + r;
    const float cw = cptr[0] * (4.0f / (float)(W * W));
    const float PAD = IS_MAX ? -1e30f : 1e30f;

    const float* rowp = in + (long)z * in_zs + (long)row * WW;
    float4 v0 = *(const float4*)(rowp + 4 * t);
    float4 v1 = *(const float4*)(rowp + 128 + 4 * t);
    float* lr = lbuf + r * 324;
    *(float4*)(lr + W + 4 * t) = v0;
    *(float4*)(lr + W + 128 + 4 * t) = v1;
    if (t < W) { lr[t] = PAD; lr[W + 256 + t] = PAD; }
    __syncthreads();

    float acc[8];
#pragma unroll
    for (int pp = 0; pp < 8; ++pp) acc[pp] = PAD;

    const float* lw = lr + 8 * t;   // window offset o=0 <-> col 8t-W ; d = o - W - pp
#pragma unroll
    for (int u = 0; u < (8 + 2 * W) / 2; ++u) {
        const float2 v = *(const float2*)(lw + 2 * u);
#pragma unroll
        for (int pp = 0; pp < 8; ++pp) {
            const int d1 = 2 * u - W - pp;
            const int d2 = d1 + 1;
            const bool ok1 = (d1 >= -W) && (d1 <= W);
            const bool ok2 = (d2 >= -W) && (d2 <= W);
            const float K1 = (float)(d1 * d1);   // compile-time literal
            const float K2 = (float)(d2 * d2);
            if (ok1 && ok2) {
                const float c1 = IS_MAX ? fmaf(cw, -K1, v.x) : fmaf(cw, K1, v.x);
                const float c2 = IS_MAX ? fmaf(cw, -K2, v.y) : fmaf(cw, K2, v.y);
                acc[pp] = IS_MAX ? fmaxf(fmaxf(acc[pp], c1), c2)
                                 : fminf(fminf(acc[pp], c1), c2);
            } else if (ok1) {
                const float c1 = IS_MAX ? fmaf(cw, -K1, v.x) : fmaf(cw, K1, v.x);
                acc[pp] = IS_MAX ? fmaxf(acc[pp], c1) : fminf(acc[pp], c1);
            } else if (ok2) {
                const float c2 = IS_MAX ? fmaf(cw, -K2, v.y) : fmaf(cw, K2, v.y);
                acc[pp] = IS_MAX ? fmaxf(acc[pp], c2) : fminf(acc[pp], c2);
            }
        }
    }
    float* op = out + (long)z * out_zs + (long)row * WW + 8 * t;
    *(float4*)(op)     = make_float4(acc[0], acc[1], acc[2], acc[3]);
    *(float4*)(op + 4) = make_float4(acc[4], acc[5], acc[6], acc[7]);
}

// ---------------- V pass: thread owns 8 consecutive rows in one column ----------------
template <int W, bool IS_MAX>
__global__ __launch_bounds__(256, 4) void vpass_k(const float* __restrict__ in,
                                                  float* __restrict__ out,
                                                  const float* __restrict__ cptr,
                                                  long in_zs, long out_zs)
{
    const int x = threadIdx.x;       // column
    const int z = blockIdx.x;        // image
    const int h0 = blockIdx.y * 8;   // first output row
    const float cw = cptr[0] * (4.0f / (float)(W * W));
    const float PAD = IS_MAX ? -1e30f : 1e30f;
    const float* img = in + (long)z * in_zs;

    float acc[8];
#pragma unroll
    for (int pp = 0; pp < 8; ++pp) acc[pp] = PAD;

    const int NR = 8 + 2 * W;        // rows visited; multiple of 8
#pragma unroll
    for (int ch = 0; ch < NR / 8; ++ch) {
        float v[8];
        // batched branchless clamped loads — all 8 issue before any use
#pragma unroll
        for (int q = 0; q < 8; ++q) {
            const int h = h0 + ch * 8 + q - W;
            const int hc = min(max(h, 0), HH - 1);
            const float tv = img[(long)hc * WW + x];
            v[q] = (h == hc) ? tv : PAD;          // uniform-cond select, no branch around load
        }
#pragma unroll
        for (int pp = 0; pp < 8; ++pp) {
#pragma unroll
            for (int q = 0; q < 8; q += 2) {
                const int d1 = ch * 8 + q - W - pp;
                const int d2 = d1 + 1;
                const bool ok1 = (d1 >= -W) && (d1 <= W);
                const bool ok2 = (d2 >= -W) && (d2 <= W);
                const float K1 = (float)(d1 * d1);
                const float K2 = (float)(d2 * d2);
                if (ok1 && ok2) {
                    const float c1 = IS_MAX ? fmaf(cw, -K1, v[q])     : fmaf(cw, K1, v[q]);
                    const float c2 = IS_MAX ? fmaf(cw, -K2, v[q + 1]) : fmaf(cw, K2, v[q + 1]);
                    acc[pp] = IS_MAX ? fmaxf(fmaxf(acc[pp], c1), c2)
                                     : fminf(fminf(acc[pp], c1), c2);
                } else if (ok1) {
                    const float c1 = IS_MAX ? fmaf(cw, -K1, v[q]) : fmaf(cw, K1, v[q]);
                    acc[pp] = IS_MAX ? fmaxf(acc[pp], c1) : fminf(acc[pp], c1);
                } else if (ok2) {
                    const float c2 = IS_MAX ? fmaf(cw, -K2, v[q + 1]) : fmaf(cw, K2, v[q + 1]);
                    acc[pp] = IS_MAX ? fmaxf(acc[pp], c2) : fminf(acc[pp], c2);
                }
            }
        }
    }
#pragma unroll
    for (int pp = 0; pp < 8; ++pp)
        out[(long)z * out_zs + (long)(h0 + pp) * WW + x] = acc[pp];
}

// ---------------- launcher: 16 lean dispatches ----------------
template <int W>
static void run_scale(const float* x, float* ws, float* outk, const float* c,
                      hipStream_t stream)
{
    dim3 g(BC, HH / 8), b(256);
    hpass_k<W, true ><<<g, b, 0, stream>>>(x,    ws,   c, HW,      HW);
    vpass_k<W, true ><<<g, b, 0, stream>>>(ws,   outk, c, HW,      (long)NS * HW);
    hpass_k<W, false><<<g, b, 0, stream>>>(outk, ws,   c, (long)NS * HW, HW);
    vpass_k<W, false><<<g, b, 0, stream>>>(ws,   outk, c, HW,      (long)NS * HW);
}

extern "C" void kernel_launch(void* const* d_in, const int* in_sizes, int n_in,
                              void* d_out, int out_size, void* d_ws, size_t ws_size,
                              hipStream_t stream)
{
    const float* x = (const float*)d_in[0];   // [4,8,256,256] fp32
    const float* c = (const float*)d_in[1];   // scalar se_coef
    float* out = (float*)d_out;               // [4,8,4,256,256] fp32
    float* ws  = (float*)d_ws;                // 8 MB ping buffer

    run_scale<4 >(x, ws, out + 0L * HW, c, stream);
    run_scale<8 >(x, ws, out + 1L * HW, c, stream);
    run_scale<16>(x, ws, out + 2L * HW, c, stream);
    run_scale<32>(x, ws, out + 3L * HW, c, stream);
}

// Round 4
// 120.362 us; speedup vs baseline: 4.2805x; 1.4556x over previous
//
#include <hip/hip_runtime.h>

// Multi-scale parabolic morphological closing, 3-dispatch fused pipeline.
// closing_k = erode_v(erode_h(dilate_v(dilate_h(x)))), W_k = {4,8,16,32},
// weight(d) = c * (4/W^2) * d^2  (power-of-two scale; fmaf bit-exact vs ref).
// Out-of-range taps use +-1e30 pad, never wins vs real data (absmax 0 R1-R3).
//
// R4: (a) all 4 scales per dispatch via blockIdx.z switch into fully-unrolled
// template bodies (no arrays -> no R2-style spills); (b) dilate_v+erode_h fused
// through an LDS tile (erode_h is row-local on dilate_v's output); (c) buffer
// rotation x->out->ws->out so no dispatch reads and writes the same buffer.
// R3 limiter was 16 serialized dispatch ramps, not VALU (20us floor) nor HBM.

#define HH 256
#define WW 256
#define BC 32
#define NS 4
#define HW (HH * WW)
#define SLICE ((long)BC * HW)
#define LSTR 324   // LDS row stride: 2*32+256+4

// ---- core: horizontal pass over one padded LDS row; thread computes 8 outputs ----
// lw = row base + 8*t ; offset o in [0, 2W+8) maps to d = o - W - pp
template <int W, bool IS_MAX>
__device__ __forceinline__ void hpass_lds(const float* __restrict__ lw, float cw,
                                          float acc[8])
{
    const float PAD = IS_MAX ? -1e30f : 1e30f;
#pragma unroll
    for (int pp = 0; pp < 8; ++pp) acc[pp] = PAD;
#pragma unroll
    for (int u = 0; u < (8 + 2 * W) / 2; ++u) {
        const float2 v = *(const float2*)(lw + 2 * u);
#pragma unroll
        for (int pp = 0; pp < 8; ++pp) {
            const int d1 = 2 * u - W - pp;
            const int d2 = d1 + 1;
            const bool ok1 = (d1 >= -W) && (d1 <= W);
            const bool ok2 = (d2 >= -W) && (d2 <= W);
            const float K1 = (float)(d1 * d1);
            const float K2 = (float)(d2 * d2);
            if (ok1 && ok2) {
                const float c1 = IS_MAX ? fmaf(cw, -K1, v.x) : fmaf(cw, K1, v.x);
                const float c2 = IS_MAX ? fmaf(cw, -K2, v.y) : fmaf(cw, K2, v.y);
                acc[pp] = IS_MAX ? fmaxf(fmaxf(acc[pp], c1), c2)
                                 : fminf(fminf(acc[pp], c1), c2);
            } else if (ok1) {
                const float c1 = IS_MAX ? fmaf(cw, -K1, v.x) : fmaf(cw, K1, v.x);
                acc[pp] = IS_MAX ? fmaxf(acc[pp], c1) : fminf(acc[pp], c1);
            } else if (ok2) {
                const float c2 = IS_MAX ? fmaf(cw, -K2, v.y) : fmaf(cw, K2, v.y);
                acc[pp] = IS_MAX ? fmaxf(acc[pp], c2) : fminf(acc[pp], c2);
            }
        }
    }
}

// ---- core: vertical pass; thread = one column, 8 consecutive output rows ----
template <int W, bool IS_MAX>
__device__ __forceinline__ void vpass_core(const float* __restrict__ img, int x,
                                           int h0, float cw, float acc[8])
{
    const float PAD = IS_MAX ? -1e30f : 1e30f;
#pragma unroll
    for (int pp = 0; pp < 8; ++pp) acc[pp] = PAD;
#pragma unroll
    for (int ch = 0; ch < (8 + 2 * W) / 8; ++ch) {
        float v[8];
#pragma unroll
        for (int q = 0; q < 8; ++q) {        // batched branchless clamped loads
            const int h = h0 + ch * 8 + q - W;
            const int hc = min(max(h, 0), HH - 1);
            const float tv = img[(long)hc * WW + x];
            v[q] = (h == hc) ? tv : PAD;
        }
#pragma unroll
        for (int pp = 0; pp < 8; ++pp) {
#pragma unroll
            for (int q = 0; q < 8; q += 2) {
                const int d1 = ch * 8 + q - W - pp;
                const int d2 = d1 + 1;
                const bool ok1 = (d1 >= -W) && (d1 <= W);
                const bool ok2 = (d2 >= -W) && (d2 <= W);
                const float K1 = (float)(d1 * d1);
                const float K2 = (float)(d2 * d2);
                if (ok1 && ok2) {
                    const float c1 = IS_MAX ? fmaf(cw, -K1, v[q])     : fmaf(cw, K1, v[q]);
                    const float c2 = IS_MAX ? fmaf(cw, -K2, v[q + 1]) : fmaf(cw, K2, v[q + 1]);
                    acc[pp] = IS_MAX ? fmaxf(fmaxf(acc[pp], c1), c2)
                                     : fminf(fminf(acc[pp], c1), c2);
                } else if (ok1) {
                    const float c1 = IS_MAX ? fmaf(cw, -K1, v[q]) : fmaf(cw, K1, v[q]);
                    acc[pp] = IS_MAX ? fmaxf(acc[pp], c1) : fminf(acc[pp], c1);
                } else if (ok2) {
                    const float c2 = IS_MAX ? fmaf(cw, -K2, v[q + 1]) : fmaf(cw, K2, v[q + 1]);
                    acc[pp] = IS_MAX ? fmaxf(acc[pp], c2) : fminf(acc[pp], c2);
                }
            }
        }
    }
}

// ================= K1: dilate_h (global -> global) =================
template <int W>
__device__ __forceinline__ void dh_impl(const float* __restrict__ ip,
                                        float* __restrict__ op_base,
                                        float c, float* lbuf)
{
    const int tid = threadIdx.x;
    const int r = tid >> 5, t = tid & 31;
    const int row = blockIdx.y * 8 + r;
    const float cw = c * (4.0f / (float)(W * W));

    const float* rowp = ip + (long)row * WW;
    float4 v0 = *(const float4*)(rowp + 4 * t);
    float4 v1 = *(const float4*)(rowp + 128 + 4 * t);
    float* lr = lbuf + r * LSTR;
    *(float4*)(lr + W + 4 * t) = v0;
    *(float4*)(lr + W + 128 + 4 * t) = v1;
    if (t < W) { lr[t] = -1e30f; lr[W + 256 + t] = -1e30f; }
    __syncthreads();

    float acc[8];
    hpass_lds<W, true>(lr + 8 * t, cw, acc);
    float* op = op_base + (long)row * WW + 8 * t;
    *(float4*)(op)     = make_float4(acc[0], acc[1], acc[2], acc[3]);
    *(float4*)(op + 4) = make_float4(acc[4], acc[5], acc[6], acc[7]);
}

__global__ __launch_bounds__(256, 4) void k1_dh(const float* __restrict__ in,
                                                float* __restrict__ out,
                                                const float* __restrict__ cptr,
                                                long in_ks, long in_zs,
                                                long out_ks, long out_zs)
{
    __shared__ float lbuf[8 * LSTR];
    const int k = blockIdx.z, z = blockIdx.x;
    const float c = cptr[0];
    const float* ip = in + (long)k * in_ks + (long)z * in_zs;
    float* op = out + (long)k * out_ks + (long)z * out_zs;
    switch (k) {
        case 0: dh_impl<4 >(ip, op, c, lbuf); break;
        case 1: dh_impl<8 >(ip, op, c, lbuf); break;
        case 2: dh_impl<16>(ip, op, c, lbuf); break;
        case 3: dh_impl<32>(ip, op, c, lbuf); break;
    }
}

// ================= K2: dilate_v + erode_h fused via LDS =================
template <int W>
__device__ __forceinline__ void dveh_impl(const float* __restrict__ img,
                                          float* __restrict__ op_base,
                                          float c, float* lbuf)
{
    const int x = threadIdx.x;
    const int h0 = blockIdx.y * 8;
    const float cw = c * (4.0f / (float)(W * W));

    // phase 1: dilate_v for 8 rows (thread-per-column)
    float vacc[8];
    vpass_core<W, true>(img, x, h0, cw, vacc);

    // to LDS as padded rows (pad = +1e30 for the following erosion)
#pragma unroll
    for (int q = 0; q < 8; ++q) lbuf[q * LSTR + W + x] = vacc[q];
    if (x < W) {
#pragma unroll
        for (int q = 0; q < 8; ++q) {
            lbuf[q * LSTR + x] = 1e30f;
            lbuf[q * LSTR + W + 256 + x] = 1e30f;
        }
    }
    __syncthreads();

    // phase 2: erode_h on the 8-row tile
    const int r = threadIdx.x >> 5, t = threadIdx.x & 31;
    float acc[8];
    hpass_lds<W, false>(lbuf + r * LSTR + 8 * t, cw, acc);
    float* op = op_base + (long)(h0 + r) * WW + 8 * t;
    *(float4*)(op)     = make_float4(acc[0], acc[1], acc[2], acc[3]);
    *(float4*)(op + 4) = make_float4(acc[4], acc[5], acc[6], acc[7]);
}

__global__ __launch_bounds__(256, 4) void k2_dveh(const float* __restrict__ in,
                                                  float* __restrict__ out,
                                                  const float* __restrict__ cptr,
                                                  long in_ks, long in_zs,
                                                  long out_ks, long out_zs)
{
    __shared__ float lbuf[8 * LSTR];
    const int k = blockIdx.z, z = blockIdx.x;
    const float c = cptr[0];
    const float* ip = in + (long)k * in_ks + (long)z * in_zs;
    float* op = out + (long)k * out_ks + (long)z * out_zs;
    switch (k) {
        case 0: dveh_impl<4 >(ip, op, c, lbuf); break;
        case 1: dveh_impl<8 >(ip, op, c, lbuf); break;
        case 2: dveh_impl<16>(ip, op, c, lbuf); break;
        case 3: dveh_impl<32>(ip, op, c, lbuf); break;
    }
}

// ================= K3: erode_v (global -> global) =================
template <int W>
__device__ __forceinline__ void ev_impl(const float* __restrict__ img,
                                        float* __restrict__ op_base, float c)
{
    const int x = threadIdx.x;
    const int h0 = blockIdx.y * 8;
    const float cw = c * (4.0f / (float)(W * W));
    float acc[8];
    vpass_core<W, false>(img, x, h0, cw, acc);
#pragma unroll
    for (int pp = 0; pp < 8; ++pp)
        op_base[(long)(h0 + pp) * WW + x] = acc[pp];
}

__global__ __launch_bounds__(256, 4) void k3_ev(const float* __restrict__ in,
                                                float* __restrict__ out,
                                                const float* __restrict__ cptr,
                                                long in_ks, long in_zs,
                                                long out_ks, long out_zs)
{
    const int k = blockIdx.z, z = blockIdx.x;
    const float c = cptr[0];
    const float* ip = in + (long)k * in_ks + (long)z * in_zs;
    float* op = out + (long)k * out_ks + (long)z * out_zs;
    switch (k) {
        case 0: ev_impl<4 >(ip, op, c); break;
        case 1: ev_impl<8 >(ip, op, c); break;
        case 2: ev_impl<16>(ip, op, c); break;
        case 3: ev_impl<32>(ip, op, c); break;
    }
}

extern "C" void kernel_launch(void* const* d_in, const int* in_sizes, int n_in,
                              void* d_out, int out_size, void* d_ws, size_t ws_size,
                              hipStream_t stream)
{
    const float* x = (const float*)d_in[0];   // [4,8,256,256] fp32
    const float* c = (const float*)d_in[1];   // scalar se_coef
    float* out = (float*)d_out;               // [4,8,4,256,256] fp32
    float* ws  = (float*)d_ws;

    dim3 b(256);
    if (ws_size >= (size_t)(NS * SLICE) * sizeof(float)) {
        // 3 merged dispatches; rotation x -> out -> ws -> out
        dim3 g(BC, HH / 8, NS);
        k1_dh  <<<g, b, 0, stream>>>(x,   out, c, 0,     HW, HW,    (long)NS * HW);
        k2_dveh<<<g, b, 0, stream>>>(out, ws,  c, HW,    (long)NS * HW, SLICE, HW);
        k3_ev  <<<g, b, 0, stream>>>(ws,  out, c, SLICE, HW, HW,    (long)NS * HW);
    } else {
        // fallback: per-scale, single 8.4 MB ws slice
        dim3 g(BC, HH / 8, 1);
        for (int k = 0; k < NS; ++k) {
            // shift k into blockIdx.z via in_ks trick is unavailable; launch with z=1
            // and bake k by pointer + template dispatch through grid.z==1 switch(k==0).
            // Simplest: reuse merged kernels with k-offset pointers and z-extent 1 is
            // wrong (switch uses blockIdx.z). Launch 4-deep grid with only scale k
            // active is wasteful; instead do 12 per-scale launches via full-z grid on
            // a single scale copy: fall back to the always-correct merged-on-out path:
            float* outk = out + (long)k * HW;
            dim3 gz(BC, HH / 8, 1);
            // per-scale kernels via blockIdx.z==0 requires case k; emulate by basing
            // pointers so case 0 is scale k is impossible -> use dedicated launches:
            switch (k) {
                case 0:
                    k1_dh  <<<gz, b, 0, stream>>>(x,    outk, c, 0, HW, 0, (long)NS * HW);
                    k2_dveh<<<gz, b, 0, stream>>>(outk, ws,   c, 0, (long)NS * HW, 0, HW);
                    k3_ev  <<<gz, b, 0, stream>>>(ws,   outk, c, 0, HW, 0, (long)NS * HW);
                    break;
                default: {
                    // shift base pointers so blockIdx.z=0 maps to scale k's template:
                    // launch grid with z extent k+1 would waste blocks; accept it only
                    // for the rare tiny-ws fallback:
                    dim3 gk(BC, HH / 8, (unsigned)(k + 1));
                    // mask: only z==k blocks do work is not expressible here; instead
                    // simply run the merged path restricted to scale k by pointer
                    // arithmetic with in_ks=0 on a z-extent-(k+1) grid would redo
                    // lower scales; that is still correct (they overwrite their own
                    // slices with identical values) but wasteful. ws has room for
                    // k+1 slices? Not guaranteed. Use z-extent (k+1) only on out:
                    k1_dh  <<<gk, b, 0, stream>>>(x,   out, c, 0, HW, HW, (long)NS * HW);
                    k2_dveh<<<gk, b, 0, stream>>>(out, ws,  c, HW, (long)NS * HW,
                                                  (long)(ws_size / sizeof(float) / (k + 1) / (BC * HW)) ? SLICE : 0, HW);
                    k3_ev  <<<gk, b, 0, stream>>>(ws,  out, c, (long)(ws_size / sizeof(float) / (k + 1) / (BC * HW)) ? SLICE : 0, HW, HW, (long)NS * HW);
                    break;
                }
            }
        }
    }
}